// Round 14
// baseline (90.643 us; speedup 1.0000x reference)
//
#include <hip/hip_runtime.h>

typedef __attribute__((ext_vector_type(4))) float f32x4;
typedef __attribute__((ext_vector_type(16))) float f32x16;
typedef __attribute__((ext_vector_type(8))) __bf16 bf16x8;
typedef __attribute__((ext_vector_type(4))) __bf16 bf16x4;
typedef __attribute__((ext_vector_type(8))) unsigned short u16x8;

#define L_SEQ 1024
#define NB 8
#define EMB 256
#define NHEAD 8
#define HD 32
#define MROWS 8192  // L_SEQ * NB
#define SZ_ELEM ((size_t)MROWS * EMB)

static __device__ __forceinline__ f32x4 mfma_bf16(bf16x8 a, bf16x8 b, f32x4 c) {
    return __builtin_amdgcn_mfma_f32_16x16x32_bf16(a, b, c, 0, 0, 0);
}
static __device__ __forceinline__ f32x16 mfma32(bf16x8 a, bf16x8 b, f32x16 c) {
    return __builtin_amdgcn_mfma_f32_32x32x16_bf16(a, b, c, 0, 0, 0);
}

// Scalar bf16 pack from floats (PROVEN R1-R13; do NOT replace with
// v_cvt_pk_bf16_f32 asm — R7 failed with it: element-order mismatch).
static __device__ __forceinline__ unsigned pack2(float a, float b) {
    union { __bf16 h; unsigned short u; } lo, hi;
    lo.h = (__bf16)a; hi.h = (__bf16)b;
    return (unsigned)lo.u | ((unsigned)hi.u << 16);
}

// v_permlane32_swap_b32: a.hi-half-lanes <-> b.lo-half-lanes (R4-R13-proven)
static __device__ __forceinline__ void permswap(unsigned &a, unsigned &b) {
    asm("v_permlane32_swap_b32 %0, %1" : "+v"(a), "+v"(b));
}

struct GemmBatch {
    const void* X[6];
    const float* W[6];
    const float* Bv[6];
    void* O[6];
    float scale[6];
};

// C[m,n] = (sum_k X[m,k] * W[n,k] + bias[n]) * scale
// R14: BM=128, BN=128, BK=64; 256 threads = 4 waves (2x2), each wave 64x64
// via 4x4 16x16 frags (128 MFMA/block). BN=128 halves the duplicate f32
// X staging/cvt (2 nblk-sharer blocks instead of 4).
// XMODE: 0 = f32 X, 1 = bf16 X.
template<int XMODE, bool OUT_F32>
__global__ __launch_bounds__(256, 2)
void gemm_kernel(GemmBatch batch) {
    __shared__ __bf16 Xl[128][72];
    __shared__ __bf16 Wl[128][72];
    const int z = blockIdx.z;
    const int fid = blockIdx.x;
    const int swz = (fid & 7) * 16 + (fid >> 3);   // 128 blocks -> 8 XCD chunks of 16
    const int nblk = swz & 1, mblk = swz >> 1;
    const float* __restrict__ W = batch.W[z];
    const float* __restrict__ bias = batch.Bv[z];
    const float scale = batch.scale[z];
    const int tid = threadIdx.x;
    const int w = tid >> 6, lane = tid & 63;
    const int g = lane >> 4, li = lane & 15;
    const int wr = w >> 1, wc = w & 1;

    f32x4 acc[4][4];
#pragma unroll
    for (int i = 0; i < 4; ++i)
#pragma unroll
        for (int j = 0; j < 4; ++j) acc[i][j] = f32x4{0.f, 0.f, 0.f, 0.f};

    for (int kk = 0; kk < 4; ++kk) {
        __syncthreads();
        if (XMODE == 1) {
            const __bf16* Xb = (const __bf16*)batch.X[z];
#pragma unroll
            for (int p = 0; p < 4; ++p) {
                int idx = tid + p * 256;
                int row = idx >> 3, c8 = (idx & 7) * 8;
                bf16x8 xv = *(const bf16x8*)(Xb + (size_t)(mblk * 128 + row) * 256 + kk * 64 + c8);
                *(bf16x8*)&Xl[row][c8] = xv;
            }
        } else {
            const float* Xf = (const float*)batch.X[z];
#pragma unroll
            for (int p = 0; p < 8; ++p) {
                int idx = tid + p * 256;
                int row = idx >> 4, c4 = (idx & 15) * 4;
                f32x4 xv = *(const f32x4*)(Xf + (size_t)(mblk * 128 + row) * 256 + kk * 64 + c4);
                bf16x4 bv;
#pragma unroll
                for (int j = 0; j < 4; ++j) bv[j] = (__bf16)xv[j];
                *(bf16x4*)&Xl[row][c4] = bv;
            }
        }
        // W tile: 128 n-rows x 64 k-cols
#pragma unroll
        for (int p = 0; p < 8; ++p) {
            int idx = tid + p * 256;
            int row = idx >> 4, c4 = (idx & 15) * 4;
            f32x4 wv = *(const f32x4*)(W + (size_t)(nblk * 128 + row) * 256 + kk * 64 + c4);
            bf16x4 bv;
#pragma unroll
            for (int j = 0; j < 4; ++j) bv[j] = (__bf16)wv[j];
            *(bf16x4*)&Wl[row][c4] = bv;
        }
        __syncthreads();
#pragma unroll
        for (int ks = 0; ks < 2; ++ks) {
            bf16x8 a[4], b[4];
#pragma unroll
            for (int af = 0; af < 4; ++af)
                a[af] = *(const bf16x8*)&Xl[wr * 64 + af * 16 + li][ks * 32 + g * 8];
#pragma unroll
            for (int bi = 0; bi < 4; ++bi)
                b[bi] = *(const bf16x8*)&Wl[wc * 64 + bi * 16 + li][ks * 32 + g * 8];
#pragma unroll
            for (int af = 0; af < 4; ++af)
#pragma unroll
                for (int bi = 0; bi < 4; ++bi)
                    acc[af][bi] = mfma_bf16(a[af], b[bi], acc[af][bi]);
        }
    }
#pragma unroll
    for (int af = 0; af < 4; ++af)
#pragma unroll
        for (int bi = 0; bi < 4; ++bi)
#pragma unroll
            for (int r = 0; r < 4; ++r) {
                int mrow = mblk * 128 + wr * 64 + af * 16 + 4 * g + r;
                int ncol = nblk * 128 + wc * 64 + bi * 16 + li;
                float v = (acc[af][bi][r] + bias[ncol]) * scale;
                if (OUT_F32)
                    ((float*)batch.O[z])[(size_t)mrow * 256 + ncol] = v;
                else
                    ((__bf16*)batch.O[z])[(size_t)mrow * 256 + ncol] = (__bf16)v;
            }
}

struct AttnArgs {
    const __bf16* Q[2];
    const __bf16* K[2];
    const __bf16* V[2];
    __bf16* AO[2];
};

// Swapped-QK^T flash attention, fixed-shift softmax (no online max).
// FROZEN at R13 (KVBLK=256, 8-wave blocks): attn converged at ~41 us across
// R9-R13 structural attempts; v_exp_f32 issue + dependency chain is the core.
__global__ __launch_bounds__(512, 4)
void attn_kernel(AttnArgs args) {
    __shared__ __bf16 Kl[256][40];   // K tile [s][d], padded
    __shared__ __bf16 Vt[32][264];   // V^T tile [d][s], padded + XOR-swizzled cols
    const int fid = blockIdx.x;
    const int swz = (fid & 7) * 64 + (fid >> 3);   // 512 -> 8 XCD chunks of 64
    const int qb = swz & 3;
    const int nh = (swz >> 2) & 63;
    const int st = swz >> 8;
    const int n = nh >> 3, h = nh & 7;
    const __bf16* __restrict__ Q = args.Q[st];
    const __bf16* __restrict__ K = args.K[st];
    const __bf16* __restrict__ V = args.V[st];
    __bf16* __restrict__ AO = args.AO[st];
    const int tid = threadIdx.x;
    const int w = tid >> 6, lane = tid & 63;
    const int q32 = lane & 31, hi = lane >> 5;

    bf16x8 qf[2];
    {
        int qrow = qb * 256 + w * 32 + q32;
#pragma unroll
        for (int kb = 0; kb < 2; ++kb)
            qf[kb] = *(const bf16x8*)(Q + ((size_t)qrow * NB + n) * EMB + h * HD + kb * 16 + hi * 8);
    }

    bf16x8 ones;
#pragma unroll
    for (int j = 0; j < 8; ++j) ones[j] = (__bf16)1.0f;
    f32x16 minit;
#pragma unroll
    for (int r = 0; r < 16; ++r) minit[r] = -12.0f;  // fixed softmax shift, hoisted

    f32x16 accO, accL;
#pragma unroll
    for (int r = 0; r < 16; ++r) { accO[r] = 0.f; accL[r] = 0.f; }

    const int vsw_r = ((q32 >> 3) & 3) << 3;   // read-side Vt column swizzle

    const int r2 = tid >> 2;                  // 0..127
    const int c8s = (tid & 3) * 8;
    const int row0 = 2 * r2;
    const int vsw_w = ((c8s >> 3) & 3) << 3;
    const int vcol0 = row0 ^ vsw_w;
    const __bf16* Kp = K + ((size_t)row0 * NB + n) * EMB + h * HD + c8s;
    const __bf16* Vp = V + ((size_t)row0 * NB + n) * EMB + h * HD + c8s;
    const size_t rstride = (size_t)NB * EMB;
    const size_t tstride = (size_t)256 * NB * EMB;

    for (int t = 0; t < 4; ++t) {
        __syncthreads();
        {
            bf16x8 k0 = *(const bf16x8*)(Kp);
            bf16x8 k1 = *(const bf16x8*)(Kp + rstride);
            bf16x8 v0 = *(const bf16x8*)(Vp);
            bf16x8 v1 = *(const bf16x8*)(Vp + rstride);
            Kp += tstride; Vp += tstride;
            *(bf16x8*)&Kl[row0][c8s] = k0;
            *(bf16x8*)&Kl[row0 + 1][c8s] = k1;
            union { bf16x8 v; u16x8 u; } b0, b1;
            b0.v = v0; b1.v = v1;
#pragma unroll
            for (int j = 0; j < 8; ++j)
                *(unsigned*)&Vt[c8s + j][vcol0] = (unsigned)b0.u[j] | ((unsigned)b1.u[j] << 16);
        }
        __syncthreads();

        f32x16 s_cur;
        {
            bf16x8 kf0 = *(const bf16x8*)&Kl[q32][hi * 8];
            bf16x8 kf1 = *(const bf16x8*)&Kl[q32][16 + hi * 8];
            s_cur = mfma32(kf0, qf[0], minit);
            s_cur = mfma32(kf1, qf[1], s_cur);
        }
#pragma unroll
        for (int sb = 0; sb < 8; ++sb) {
            f32x16 s_next;
            if (sb < 7) {
                bf16x8 nkf0 = *(const bf16x8*)&Kl[(sb + 1) * 32 + q32][hi * 8];
                bf16x8 nkf1 = *(const bf16x8*)&Kl[(sb + 1) * 32 + q32][16 + hi * 8];
                s_next = mfma32(nkf0, qf[0], minit);
                s_next = mfma32(nkf1, qf[1], s_next);
            }
            float p[16];
#pragma unroll
            for (int r = 0; r < 16; ++r) p[r] = __builtin_amdgcn_exp2f(s_cur[r]);

            bf16x8 pa[2];
#pragma unroll
            for (int ks = 0; ks < 2; ++ks) {
                unsigned x0 = pack2(p[8 * ks + 0], p[8 * ks + 1]);
                unsigned x1 = pack2(p[8 * ks + 2], p[8 * ks + 3]);
                unsigned x2 = pack2(p[8 * ks + 4], p[8 * ks + 5]);
                unsigned x3 = pack2(p[8 * ks + 6], p[8 * ks + 7]);
                permswap(x0, x2);
                permswap(x1, x3);
                union { unsigned u[4]; bf16x8 v; } cvt;
                cvt.u[0] = x0; cvt.u[1] = x1; cvt.u[2] = x2; cvt.u[3] = x3;
                pa[ks] = cvt.v;
            }
            bf16x8 vf0 = *(const bf16x8*)&Vt[q32][(sb * 32 + hi * 8) ^ vsw_r];
            bf16x8 vf1 = *(const bf16x8*)&Vt[q32][(sb * 32 + 16 + hi * 8) ^ vsw_r];
            __builtin_amdgcn_s_setprio(1);
            accO = mfma32(pa[0], vf0, accO);
            accL = mfma32(pa[0], ones, accL);
            accO = mfma32(pa[1], vf1, accO);
            accL = mfma32(pa[1], ones, accL);
            __builtin_amdgcn_s_setprio(0);
            if (sb < 7) s_cur = s_next;
        }
    }

#pragma unroll
    for (int r = 0; r < 16; ++r) {
        int crow = (r & 3) + 8 * (r >> 2) + 4 * hi;
        int row = qb * 256 + w * 32 + crow;
        AO[((size_t)row * NB + n) * EMB + h * HD + q32] = (__bf16)(accO[r] / accL[r]);
    }
}

extern "C" void kernel_launch(void* const* d_in, const int* in_sizes, int n_in,
                              void* d_out, int out_size, void* d_ws, size_t ws_size,
                              hipStream_t stream) {
    const size_t SZ = SZ_ELEM;
    __bf16* wsb = (__bf16*)d_ws;
    __bf16* arr[8];
    for (int i = 0; i < 8; ++i) arr[i] = wsb + (size_t)i * SZ;

    // 1/sqrt(32) * log2(e): fold attention scale + exp2 conversion into Q
    const float qscale = 0.25504310349362475f;

    GemmBatch pb{};
    for (int s = 0; s < 6; ++s) {
        pb.X[s] = d_in[s];
        pb.W[s] = (const float*)d_in[6 + s];
        pb.Bv[s] = (const float*)d_in[14 + s];
        pb.O[s] = arr[s];
        pb.scale[s] = (s == 0 || s == 3) ? qscale : 1.0f;
    }
    hipLaunchKernelGGL((gemm_kernel<0, false>), dim3(128, 1, 6), dim3(256), 0, stream, pb);

    AttnArgs aa{};
    aa.Q[0] = arr[0]; aa.K[0] = arr[1]; aa.V[0] = arr[2]; aa.AO[0] = arr[6];
    aa.Q[1] = arr[3]; aa.K[1] = arr[4]; aa.V[1] = arr[5]; aa.AO[1] = arr[7];
    hipLaunchKernelGGL(attn_kernel, dim3(512), dim3(512), 0, stream, aa);

    GemmBatch ob{};
    for (int s = 0; s < 2; ++s) {
        ob.X[s] = arr[6 + s];
        ob.W[s] = (const float*)d_in[12 + s];
        ob.Bv[s] = (const float*)d_in[20 + s];
        ob.O[s] = (float*)d_out + (size_t)s * SZ;
        ob.scale[s] = 1.0f;
    }
    hipLaunchKernelGGL((gemm_kernel<1, true>), dim3(128, 1, 2), dim3(256), 0, stream, ob);
}

// Round 15
// 69.381 us; speedup vs baseline: 1.3064x; 1.3064x over previous
//
#include <hip/hip_runtime.h>

typedef __attribute__((ext_vector_type(4))) float f32x4;
typedef __attribute__((ext_vector_type(16))) float f32x16;
typedef __attribute__((ext_vector_type(8))) __bf16 bf16x8;
typedef __attribute__((ext_vector_type(4))) __bf16 bf16x4;
typedef __attribute__((ext_vector_type(8))) unsigned short u16x8;

#define L_SEQ 1024
#define NB 8
#define EMB 256
#define NHEAD 8
#define HD 32
#define MROWS 8192  // L_SEQ * NB
#define SZ_ELEM ((size_t)MROWS * EMB)

static __device__ __forceinline__ f32x4 mfma_bf16(bf16x8 a, bf16x8 b, f32x4 c) {
    return __builtin_amdgcn_mfma_f32_16x16x32_bf16(a, b, c, 0, 0, 0);
}
static __device__ __forceinline__ f32x16 mfma32(bf16x8 a, bf16x8 b, f32x16 c) {
    return __builtin_amdgcn_mfma_f32_32x32x16_bf16(a, b, c, 0, 0, 0);
}

// Scalar bf16 pack from floats (PROVEN R1-R13; do NOT replace with
// v_cvt_pk_bf16_f32 asm — R7 failed with it: element-order mismatch).
static __device__ __forceinline__ unsigned pack2(float a, float b) {
    union { __bf16 h; unsigned short u; } lo, hi;
    lo.h = (__bf16)a; hi.h = (__bf16)b;
    return (unsigned)lo.u | ((unsigned)hi.u << 16);
}

// v_permlane32_swap_b32: a.hi-half-lanes <-> b.lo-half-lanes (R4-R13-proven)
static __device__ __forceinline__ void permswap(unsigned &a, unsigned &b) {
    asm("v_permlane32_swap_b32 %0, %1" : "+v"(a), "+v"(b));
}

struct GemmBatch {
    const void* X[6];
    const float* W[6];
    const float* Bv[6];
    void* O[6];
    float scale[6];
};

// C[m,n] = (sum_k X[m,k] * W[n,k] + bias[n]) * scale
// R15: back to the R13-proven BM=128, BN=64, BK=64 shape (R14's BN=128 was
// latency-bound: 3 blocks/CU lost cross-block overlap). One change: LDS
// padding 72->68 (stride 136 B -> bank = 2*row mod 32, strictly conflict-free
// vs 2-way alias at 72; also 26.1 KB -> 6 blocks/CU fits the 6-resident grid).
// XMODE: 0 = f32 X, 1 = bf16 X.
template<int XMODE, bool OUT_F32>
__global__ __launch_bounds__(256, 2)
void gemm_kernel(GemmBatch batch) {
    __shared__ __bf16 Xl[128][68];
    __shared__ __bf16 Wl[64][68];
    const int z = blockIdx.z;
    const int fid = blockIdx.x;
    const int swz = (fid & 7) * 32 + (fid >> 3);   // 256 blocks -> 8 XCD chunks of 32
    const int nblk = swz & 3, mblk = swz >> 2;
    const float* __restrict__ W = batch.W[z];
    const float* __restrict__ bias = batch.Bv[z];
    const float scale = batch.scale[z];
    const int tid = threadIdx.x;
    const int w = tid >> 6, lane = tid & 63;
    const int g = lane >> 4, li = lane & 15;
    const int wr = w >> 1, wc = w & 1;

    f32x4 acc[4][2];
#pragma unroll
    for (int i = 0; i < 4; ++i)
#pragma unroll
        for (int j = 0; j < 2; ++j) acc[i][j] = f32x4{0.f, 0.f, 0.f, 0.f};

    for (int kk = 0; kk < 4; ++kk) {
        __syncthreads();
        if (XMODE == 1) {
            const __bf16* Xb = (const __bf16*)batch.X[z];
#pragma unroll
            for (int p = 0; p < 4; ++p) {
                int idx = tid + p * 256;
                int row = idx >> 3, c8 = (idx & 7) * 8;
                bf16x8 xv = *(const bf16x8*)(Xb + (size_t)(mblk * 128 + row) * 256 + kk * 64 + c8);
                *(bf16x8*)&Xl[row][c8] = xv;
            }
        } else {
            const float* Xf = (const float*)batch.X[z];
#pragma unroll
            for (int p = 0; p < 8; ++p) {
                int idx = tid + p * 256;
                int row = idx >> 4, c4 = (idx & 15) * 4;
                f32x4 xv = *(const f32x4*)(Xf + (size_t)(mblk * 128 + row) * 256 + kk * 64 + c4);
                bf16x4 bv;
#pragma unroll
                for (int j = 0; j < 4; ++j) bv[j] = (__bf16)xv[j];
                *(bf16x4*)&Xl[row][c4] = bv;
            }
        }
#pragma unroll
        for (int p = 0; p < 4; ++p) {
            int idx = tid + p * 256;
            int row = idx >> 4, c4 = (idx & 15) * 4;
            f32x4 wv = *(const f32x4*)(W + (size_t)(nblk * 64 + row) * 256 + kk * 64 + c4);
            bf16x4 bv;
#pragma unroll
            for (int j = 0; j < 4; ++j) bv[j] = (__bf16)wv[j];
            *(bf16x4*)&Wl[row][c4] = bv;
        }
        __syncthreads();
#pragma unroll
        for (int ks = 0; ks < 2; ++ks) {
            bf16x8 a[4], b[2];
#pragma unroll
            for (int af = 0; af < 4; ++af)
                a[af] = *(const bf16x8*)&Xl[wr * 64 + af * 16 + li][ks * 32 + g * 8];
#pragma unroll
            for (int bi = 0; bi < 2; ++bi)
                b[bi] = *(const bf16x8*)&Wl[wc * 32 + bi * 16 + li][ks * 32 + g * 8];
#pragma unroll
            for (int af = 0; af < 4; ++af)
#pragma unroll
                for (int bi = 0; bi < 2; ++bi)
                    acc[af][bi] = mfma_bf16(a[af], b[bi], acc[af][bi]);
        }
    }
#pragma unroll
    for (int af = 0; af < 4; ++af)
#pragma unroll
        for (int bi = 0; bi < 2; ++bi)
#pragma unroll
            for (int r = 0; r < 4; ++r) {
                int mrow = mblk * 128 + wr * 64 + af * 16 + 4 * g + r;
                int ncol = nblk * 64 + wc * 32 + bi * 16 + li;
                float v = (acc[af][bi][r] + bias[ncol]) * scale;
                if (OUT_F32)
                    ((float*)batch.O[z])[(size_t)mrow * 256 + ncol] = v;
                else
                    ((__bf16*)batch.O[z])[(size_t)mrow * 256 + ncol] = (__bf16)v;
            }
}

struct AttnArgs {
    const __bf16* Q[2];
    const __bf16* K[2];
    const __bf16* V[2];
    __bf16* AO[2];
};

// Swapped-QK^T flash attention, fixed-shift softmax (no online max).
// FROZEN at R13 (KVBLK=256, 8-wave blocks): attn converged at ~41 us across
// R9-R13 structural attempts; v_exp_f32 issue + dependency chain is the core.
__global__ __launch_bounds__(512, 4)
void attn_kernel(AttnArgs args) {
    __shared__ __bf16 Kl[256][40];   // K tile [s][d], padded
    __shared__ __bf16 Vt[32][264];   // V^T tile [d][s], padded + XOR-swizzled cols
    const int fid = blockIdx.x;
    const int swz = (fid & 7) * 64 + (fid >> 3);   // 512 -> 8 XCD chunks of 64
    const int qb = swz & 3;
    const int nh = (swz >> 2) & 63;
    const int st = swz >> 8;
    const int n = nh >> 3, h = nh & 7;
    const __bf16* __restrict__ Q = args.Q[st];
    const __bf16* __restrict__ K = args.K[st];
    const __bf16* __restrict__ V = args.V[st];
    __bf16* __restrict__ AO = args.AO[st];
    const int tid = threadIdx.x;
    const int w = tid >> 6, lane = tid & 63;
    const int q32 = lane & 31, hi = lane >> 5;

    bf16x8 qf[2];
    {
        int qrow = qb * 256 + w * 32 + q32;
#pragma unroll
        for (int kb = 0; kb < 2; ++kb)
            qf[kb] = *(const bf16x8*)(Q + ((size_t)qrow * NB + n) * EMB + h * HD + kb * 16 + hi * 8);
    }

    bf16x8 ones;
#pragma unroll
    for (int j = 0; j < 8; ++j) ones[j] = (__bf16)1.0f;
    f32x16 minit;
#pragma unroll
    for (int r = 0; r < 16; ++r) minit[r] = -12.0f;  // fixed softmax shift, hoisted

    f32x16 accO, accL;
#pragma unroll
    for (int r = 0; r < 16; ++r) { accO[r] = 0.f; accL[r] = 0.f; }

    const int vsw_r = ((q32 >> 3) & 3) << 3;   // read-side Vt column swizzle

    const int r2 = tid >> 2;                  // 0..127
    const int c8s = (tid & 3) * 8;
    const int row0 = 2 * r2;
    const int vsw_w = ((c8s >> 3) & 3) << 3;
    const int vcol0 = row0 ^ vsw_w;
    const __bf16* Kp = K + ((size_t)row0 * NB + n) * EMB + h * HD + c8s;
    const __bf16* Vp = V + ((size_t)row0 * NB + n) * EMB + h * HD + c8s;
    const size_t rstride = (size_t)NB * EMB;
    const size_t tstride = (size_t)256 * NB * EMB;

    for (int t = 0; t < 4; ++t) {
        __syncthreads();
        {
            bf16x8 k0 = *(const bf16x8*)(Kp);
            bf16x8 k1 = *(const bf16x8*)(Kp + rstride);
            bf16x8 v0 = *(const bf16x8*)(Vp);
            bf16x8 v1 = *(const bf16x8*)(Vp + rstride);
            Kp += tstride; Vp += tstride;
            *(bf16x8*)&Kl[row0][c8s] = k0;
            *(bf16x8*)&Kl[row0 + 1][c8s] = k1;
            union { bf16x8 v; u16x8 u; } b0, b1;
            b0.v = v0; b1.v = v1;
#pragma unroll
            for (int j = 0; j < 8; ++j)
                *(unsigned*)&Vt[c8s + j][vcol0] = (unsigned)b0.u[j] | ((unsigned)b1.u[j] << 16);
        }
        __syncthreads();

        f32x16 s_cur;
        {
            bf16x8 kf0 = *(const bf16x8*)&Kl[q32][hi * 8];
            bf16x8 kf1 = *(const bf16x8*)&Kl[q32][16 + hi * 8];
            s_cur = mfma32(kf0, qf[0], minit);
            s_cur = mfma32(kf1, qf[1], s_cur);
        }
#pragma unroll
        for (int sb = 0; sb < 8; ++sb) {
            f32x16 s_next;
            if (sb < 7) {
                bf16x8 nkf0 = *(const bf16x8*)&Kl[(sb + 1) * 32 + q32][hi * 8];
                bf16x8 nkf1 = *(const bf16x8*)&Kl[(sb + 1) * 32 + q32][16 + hi * 8];
                s_next = mfma32(nkf0, qf[0], minit);
                s_next = mfma32(nkf1, qf[1], s_next);
            }
            float p[16];
#pragma unroll
            for (int r = 0; r < 16; ++r) p[r] = __builtin_amdgcn_exp2f(s_cur[r]);

            bf16x8 pa[2];
#pragma unroll
            for (int ks = 0; ks < 2; ++ks) {
                unsigned x0 = pack2(p[8 * ks + 0], p[8 * ks + 1]);
                unsigned x1 = pack2(p[8 * ks + 2], p[8 * ks + 3]);
                unsigned x2 = pack2(p[8 * ks + 4], p[8 * ks + 5]);
                unsigned x3 = pack2(p[8 * ks + 6], p[8 * ks + 7]);
                permswap(x0, x2);
                permswap(x1, x3);
                union { unsigned u[4]; bf16x8 v; } cvt;
                cvt.u[0] = x0; cvt.u[1] = x1; cvt.u[2] = x2; cvt.u[3] = x3;
                pa[ks] = cvt.v;
            }
            bf16x8 vf0 = *(const bf16x8*)&Vt[q32][(sb * 32 + hi * 8) ^ vsw_r];
            bf16x8 vf1 = *(const bf16x8*)&Vt[q32][(sb * 32 + 16 + hi * 8) ^ vsw_r];
            __builtin_amdgcn_s_setprio(1);
            accO = mfma32(pa[0], vf0, accO);
            accL = mfma32(pa[0], ones, accL);
            accO = mfma32(pa[1], vf1, accO);
            accL = mfma32(pa[1], ones, accL);
            __builtin_amdgcn_s_setprio(0);
            if (sb < 7) s_cur = s_next;
        }
    }

#pragma unroll
    for (int r = 0; r < 16; ++r) {
        int crow = (r & 3) + 8 * (r >> 2) + 4 * hi;
        int row = qb * 256 + w * 32 + crow;
        AO[((size_t)row * NB + n) * EMB + h * HD + q32] = (__bf16)(accO[r] / accL[r]);
    }
}

extern "C" void kernel_launch(void* const* d_in, const int* in_sizes, int n_in,
                              void* d_out, int out_size, void* d_ws, size_t ws_size,
                              hipStream_t stream) {
    const size_t SZ = SZ_ELEM;
    __bf16* wsb = (__bf16*)d_ws;
    __bf16* arr[8];
    for (int i = 0; i < 8; ++i) arr[i] = wsb + (size_t)i * SZ;

    // 1/sqrt(32) * log2(e): fold attention scale + exp2 conversion into Q
    const float qscale = 0.25504310349362475f;

    GemmBatch pb{};
    for (int s = 0; s < 6; ++s) {
        pb.X[s] = d_in[s];
        pb.W[s] = (const float*)d_in[6 + s];
        pb.Bv[s] = (const float*)d_in[14 + s];
        pb.O[s] = arr[s];
        pb.scale[s] = (s == 0 || s == 3) ? qscale : 1.0f;
    }
    hipLaunchKernelGGL((gemm_kernel<0, false>), dim3(256, 1, 6), dim3(256), 0, stream, pb);

    AttnArgs aa{};
    aa.Q[0] = arr[0]; aa.K[0] = arr[1]; aa.V[0] = arr[2]; aa.AO[0] = arr[6];
    aa.Q[1] = arr[3]; aa.K[1] = arr[4]; aa.V[1] = arr[5]; aa.AO[1] = arr[7];
    hipLaunchKernelGGL(attn_kernel, dim3(512), dim3(512), 0, stream, aa);

    GemmBatch ob{};
    for (int s = 0; s < 2; ++s) {
        ob.X[s] = arr[6 + s];
        ob.W[s] = (const float*)d_in[12 + s];
        ob.Bv[s] = (const float*)d_in[20 + s];
        ob.O[s] = (float*)d_out + (size_t)s * SZ;
        ob.scale[s] = 1.0f;
    }
    hipLaunchKernelGGL((gemm_kernel<1, true>), dim3(256, 1, 2), dim3(256), 0, stream, ob);
}